// Round 20
// baseline (212.879 us; speedup 1.0000x reference)
//
#include <hip/hip_runtime.h>
#include <stdint.h>
#include <stddef.h>

typedef __bf16 bf16;
typedef __attribute__((ext_vector_type(4))) float f32x4;
typedef __attribute__((ext_vector_type(16))) float f32x16;
typedef __attribute__((ext_vector_type(8))) bf16 bf16x8;
typedef __attribute__((ext_vector_type(4))) bf16 bf16x4;

#define INST_STRIDE (2048 * 64)

static __device__ __forceinline__ f32x4 mfma16(bf16x8 a, bf16x8 b, f32x4 c) {
  return __builtin_amdgcn_mfma_f32_16x16x32_bf16(a, b, c, 0, 0, 0);
}
static __device__ __forceinline__ f32x16 mfma32(bf16x8 a, bf16x8 b, f32x16 c) {
  return __builtin_amdgcn_mfma_f32_32x32x16_bf16(a, b, c, 0, 0, 0);
}
static __device__ __forceinline__ void gload16(const void* g, void* l) {
  __builtin_amdgcn_global_load_lds(
      (const __attribute__((address_space(1))) void*)g,
      (__attribute__((address_space(3))) void*)l, 16, 0, 0);
}
static __device__ __forceinline__ float exp2_fast(float x) {
  float r;
  asm("v_exp_f32 %0, %1" : "=v"(r) : "v"(x));
  return r;
}

// ---------------- weight f32 -> bf16 convert ----------------
__global__ void convert_w(const float* __restrict__ Wqkv, const float* __restrict__ Wo,
                          bf16* __restrict__ wq, bf16* __restrict__ wo) {
  int idx = blockIdx.x * 256 + threadIdx.x;
  const int NQ = 3 * 768 * 768 / 4;
  const float4* src;
  bf16* dst;
  int i;
  if (idx < NQ) { src = (const float4*)Wqkv; dst = wq; i = idx; }
  else          { src = (const float4*)Wo;   dst = wo; i = idx - NQ; }
  float4 v = src[i];
  bf16x4 o = { (bf16)v.x, (bf16)v.y, (bf16)v.z, (bf16)v.w };
  *(bf16x4*)(dst + (size_t)i * 4) = o;
}

// ---------------- QKV GEMM: 64x256 tiles, 1344 blocks (4 blocks/CU), packed Q/V ----
__launch_bounds__(512, 2)
__global__ void qkv_gemm(const float* __restrict__ Xq, const float* __restrict__ Xk,
                         const float* __restrict__ Xv, const bf16* __restrict__ Wb,
                         const float* __restrict__ bqkv, bf16* __restrict__ qg,
                         bf16* __restrict__ kg, bf16* __restrict__ vtg) {
  __shared__ __align__(16) bf16 lA[64 * 64];    // 8 KB
  __shared__ __align__(16) bf16 lB[256 * 64];   // 32 KB
  const int z = blockIdx.z;
  const float* __restrict__ X = (z == 0) ? Xq : ((z == 1) ? Xk : Xv);
  const int bx = blockIdx.x;
  int g, mt;
  if (bx < 256)      { g = 0; mt = bx; }
  else if (bx < 384) { g = 1; mt = bx - 256; }
  else               { g = 2; mt = bx - 384; }
  const int gshift = 13 - g;
  const int gpbm = (8192 >> g) - 1;
  const int ibase = (g == 2) ? 24 : (g << 4);
  const int nseg = 4 >> g;

  const int tid = threadIdx.x;
  const int lane = tid & 63, w = tid >> 6;
  const int wr = w >> 2, wc = w & 3;            // 2(M) x 4(N) waves; per-wave 32x64
  const int l15 = lane & 15, lg = lane >> 4;

  auto maprow = [&](int G) -> size_t {
    int bb = G >> gshift;
    int loc = G & gpbm;
    int seg = loc >> 11, tq = loc & 2047;
    int token = (seg << (11 + g)) + g + (tq << g);
    return (size_t)(bb * 8192 + token);
  };

  // A staging: 1 chunk/thread (64 rows x 8 chunks)
  const int c8 = tid & 7;
  const int rrow = tid >> 3;                    // 0..63
  const size_t arow = maprow(mt * 64 + rrow);

  f32x4 acc[2][4];
#pragma unroll
  for (int i = 0; i < 2; ++i)
#pragma unroll
    for (int j = 0; j < 4; ++j) acc[i][j] = (f32x4){0.f, 0.f, 0.f, 0.f};

  for (int t = 0; t < 12; ++t) {
    const int k0 = t * 64;
#pragma unroll
    for (int j = 0; j < 4; ++j) {
      int region = w * 4 + j;
      int row = region * 8 + (lane >> 3);
      int cb = lane & 7;
      const bf16* src = Wb + (size_t)(z * 768 + g * 256 + row) * 768 + k0 + ((cb ^ (row & 7)) << 3);
      gload16(src, (char*)lB + region * 1024);
    }
    {
      const float* src = X + arow * 768 + k0 + c8 * 8;
      float4 v0 = ((const float4*)src)[0];
      float4 v1 = ((const float4*)src)[1];
      bf16x8 o = { (bf16)v0.x, (bf16)v0.y, (bf16)v0.z, (bf16)v0.w,
                   (bf16)v1.x, (bf16)v1.y, (bf16)v1.z, (bf16)v1.w };
      *(bf16x8*)((char*)lA + rrow * 128 + ((c8 ^ (rrow & 7)) << 4)) = o;
    }
    __syncthreads();
#pragma unroll
    for (int ks = 0; ks < 2; ++ks) {
      bf16x8 af[2], bfr[4];
#pragma unroll
      for (int i = 0; i < 2; ++i) {
        int row = wr * 32 + i * 16 + l15;
        af[i] = *(const bf16x8*)((const char*)lA + row * 128 + (((ks * 4 + lg) ^ (row & 7)) << 4));
      }
#pragma unroll
      for (int j = 0; j < 4; ++j) {
        int col = wc * 64 + j * 16 + l15;
        bfr[j] = *(const bf16x8*)((const char*)lB + col * 128 + (((ks * 4 + lg) ^ (col & 7)) << 4));
      }
      __builtin_amdgcn_s_setprio(1);
#pragma unroll
      for (int i = 0; i < 2; ++i)
#pragma unroll
        for (int j = 0; j < 4; ++j) acc[i][j] = mfma16(af[i], bfr[j], acc[i][j]);
      __builtin_amdgcn_s_setprio(0);
    }
    __syncthreads();
  }
  // epilogue: bias + direct store into gathered layouts (all rows valid).
#pragma unroll
  for (int j = 0; j < 4; ++j) {
    int col = wc * 64 + j * 16 + l15;
    float bias = bqkv[z * 768 + g * 256 + col];
    int hg = col >> 6, d = col & 63;
    int ho = ibase + hg * nseg;
#pragma unroll
    for (int i = 0; i < 2; ++i) {
      int G0 = mt * 64 + wr * 32 + i * 16 + (lg << 2);
      if (z == 2) {
        int bb = G0 >> gshift;
        int loc = G0 & gpbm;
        int seg = loc >> 11, tq = loc & 2047;
        size_t io = (size_t)(bb * 28 + ho + seg) * INST_STRIDE;
        int tsw = (tq & ~63) | ((((tq >> 3) & 7) ^ (d & 7)) << 3) | (tq & 7);
        bf16x4 pk = { (bf16)(acc[i][j][0] + bias), (bf16)(acc[i][j][1] + bias),
                      (bf16)(acc[i][j][2] + bias), (bf16)(acc[i][j][3] + bias) };
        *(bf16x4*)(vtg + io + (size_t)d * 2048 + tsw) = pk;
      } else if (z == 0) {
        int bb = G0 >> gshift;
        int loc = G0 & gpbm;
        int seg = loc >> 11, tq = loc & 2047;
        size_t io = (size_t)(bb * 28 + ho + seg) * INST_STRIDE;
        const float s = 0.180336880f;
        bf16x4 pk = { (bf16)((acc[i][j][0] + bias) * s), (bf16)((acc[i][j][1] + bias) * s),
                      (bf16)((acc[i][j][2] + bias) * s), (bf16)((acc[i][j][3] + bias) * s) };
        *(bf16x4*)(qg + io + (size_t)d * 2048 + tq) = pk;
      } else {
#pragma unroll
        for (int reg = 0; reg < 4; ++reg) {
          int G = G0 + reg;
          int bb = G >> gshift;
          int loc = G & gpbm;
          int seg = loc >> 11, tq = loc & 2047;
          size_t io = (size_t)(bb * 28 + ho + seg) * INST_STRIDE;
          float v = acc[i][j][reg] + bias;
          int dsw = (d & 7) | (((d >> 3) ^ (tq & 7)) << 3);
          kg[io + tq * 64 + dsw] = (bf16)v;
        }
      }
    }
  }
}

// ---------------- flash attention: swapped-QK^T, no-max log2 softmax ----------------
#define CVTPK(lo_, hi_, out_) \
  asm("v_cvt_pk_bf16_f32 %0, %1, %2" : "=v"(out_) : "v"(lo_), "v"(hi_))

#define MAKE_PA(sv, kb2, dst)                                              \
  do {                                                                     \
    float p0 = exp2_fast(sv[kb2 * 8 + 0]);                                 \
    float p1 = exp2_fast(sv[kb2 * 8 + 1]);                                 \
    float p2 = exp2_fast(sv[kb2 * 8 + 2]);                                 \
    float p3 = exp2_fast(sv[kb2 * 8 + 3]);                                 \
    float p4 = exp2_fast(sv[kb2 * 8 + 4]);                                 \
    float p5 = exp2_fast(sv[kb2 * 8 + 5]);                                 \
    float p6 = exp2_fast(sv[kb2 * 8 + 6]);                                 \
    float p7 = exp2_fast(sv[kb2 * 8 + 7]);                                 \
    rs += (p0 + p1) + (p2 + p3) + ((p4 + p5) + (p6 + p7));                 \
    uint32_t a0, a1, a2, a3;                                               \
    CVTPK(p0, p1, a0); CVTPK(p2, p3, a1);                                  \
    CVTPK(p4, p5, a2); CVTPK(p6, p7, a3);                                  \
    asm("v_permlane32_swap_b32 %0, %1" : "+v"(a0), "+v"(a2));              \
    asm("v_permlane32_swap_b32 %0, %1" : "+v"(a1), "+v"(a3));              \
    union { uint32_t u[4]; bf16x8 v; } pk_;                                \
    pk_.u[0] = a0; pk_.u[1] = a1; pk_.u[2] = a2; pk_.u[3] = a3;            \
    dst = pk_.v;                                                           \
  } while (0)

__launch_bounds__(256, 2)
__global__ void attn(const bf16* __restrict__ qg, const bf16* __restrict__ kg,
                     const bf16* __restrict__ vtg, bf16* __restrict__ og,
                     const int* __restrict__ causal_p) {
  __shared__ __align__(16) bf16 lK[2][64 * 64];
  __shared__ __align__(16) bf16 lV[2][64 * 64];
  __shared__ float lSc[4][32];
  const int L = blockIdx.x + (blockIdx.y << 4);
  const int inst = (L & 7) * 7 + ((L >> 3) >> 4);
  const int qt = (L >> 3) & 15;
  const int tid = threadIdx.x, lane = tid & 63, w = tid >> 6;
  const int l31 = lane & 31, hi = lane >> 5;
  const int causal = causal_p[0];
  const size_t ib = (size_t)inst * INST_STRIDE;
  const int qbase = qt * 128 + w * 32;

  // Q fragments from d-major qg
  bf16x8 qf[4];
#pragma unroll
  for (int dt4 = 0; dt4 < 4; ++dt4) {
    bf16x8 v;
#pragma unroll
    for (int e = 0; e < 8; ++e)
      v[e] = qg[ib + (size_t)(dt4 * 16 + hi * 8 + e) * 2048 + qbase + l31];
    qf[dt4] = v;
  }

  int off0[4], off1[4];
#pragma unroll
  for (int c = 0; c < 4; ++c) {
    off0[c] = l31 * 128 + (((c * 2 + hi) ^ (l31 & 7)) << 4);
    off1[c] = (32 + l31) * 128 + (((c * 2 + hi) ^ (l31 & 7)) << 4);
  }

  f32x16 oacc0 = {0}, oacc1 = {0};
  float l = 0.f;

#define STAGE_AT(buf, kt_)                                                       \
  do {                                                                           \
    _Pragma("unroll") for (int j = 0; j < 2; ++j) {                              \
      int region = w * 2 + j;                                                    \
      int r = region * 8 + (lane >> 3);                                          \
      int cb = lane & 7;                                                         \
      gload16(kg + ib + (size_t)((kt_) + r) * 64 + cb * 8,                       \
              (char*)lK[buf] + region * 1024);                                   \
      gload16(vtg + ib + (size_t)r * 2048 + (kt_) + cb * 8,                      \
              (char*)lV[buf] + region * 1024);                                   \
    }                                                                            \
  } while (0)

  STAGE_AT(0, 0);
  __syncthreads();
  int cur = 0;
  for (int kt = 0; kt < 2048; kt += 64) {
    if (kt + 64 < 2048) STAGE_AT(cur ^ 1, kt + 64);
    const char* K = (const char*)lK[cur];
    const char* V = (const char*)lV[cur];
    f32x16 st0 = {0}, st1 = {0};
    __builtin_amdgcn_s_setprio(1);
#pragma unroll
    for (int dt4 = 0; dt4 < 4; ++dt4) {
      bf16x8 kf0 = *(const bf16x8*)(K + off0[dt4]);
      bf16x8 kf1 = *(const bf16x8*)(K + off1[dt4]);
      st0 = mfma32(kf0, qf[dt4], st0);
      st1 = mfma32(kf1, qf[dt4], st1);
    }
    __builtin_amdgcn_s_setprio(0);
    if (causal) {
      int q = qbase + l31;
#pragma unroll
      for (int r = 0; r < 16; ++r) {
        int kl = (r & 3) + 8 * (r >> 2) + 4 * hi;
        if (kt + kl > q) st0[r] = -1e30f;
        if (kt + 32 + kl > q) st1[r] = -1e30f;
      }
    }
    float rs = 0.f;
    bf16x8 pa0, pa1, pa2, pa3;
    MAKE_PA(st0, 0, pa0);
    MAKE_PA(st0, 1, pa1);
    MAKE_PA(st1, 0, pa2);
    MAKE_PA(st1, 1, pa3);
    rs += __shfl_xor(rs, 32);
    l += rs;
    __builtin_amdgcn_s_setprio(1);
#pragma unroll
    for (int kb = 0; kb < 4; ++kb) {
      bf16x8 pak = (kb == 0) ? pa0 : (kb == 1) ? pa1 : (kb == 2) ? pa2 : pa3;
      bf16x8 vf0 = *(const bf16x8*)(V + off0[kb]);
      bf16x8 vf1 = *(const bf16x8*)(V + off1[kb]);
      oacc0 = mfma32(pak, vf0, oacc0);
      oacc1 = mfma32(pak, vf1, oacc1);
    }
    __builtin_amdgcn_s_setprio(0);
    __syncthreads();
    cur ^= 1;
  }
  if (!hi) lSc[w][l31] = 1.f / l;
  asm volatile("s_waitcnt lgkmcnt(0)" ::: "memory");
  __builtin_amdgcn_sched_barrier(0);
#pragma unroll
  for (int r = 0; r < 16; ++r) {
    int ql = (r & 3) + 8 * (r >> 2) + 4 * hi;
    float linv = lSc[w][ql];
    int q = qbase + ql;
    og[ib + (size_t)q * 64 + l31] = (bf16)(oacc0[r] * linv);
    og[ib + (size_t)q * 64 + 32 + l31] = (bf16)(oacc1[r] * linv);
  }
}

// ---------------- gather + LayerNorm (one wave per token) ----------------
__global__ void ln_gather(const bf16* __restrict__ og, const float* __restrict__ lnw,
                          const float* __restrict__ lnb, bf16* __restrict__ xnorm) {
  const int tok = blockIdx.x * 4 + (threadIdx.x >> 6);
  const int lane = threadIdx.x & 63;
  const int bb = tok >> 13, n = tok & 8191;
  float vals[12];
#pragma unroll
  for (int h = 0; h < 12; ++h) {
    const int grp = h >> 2, hg = h & 3;
    const int sl = 11 + grp;
    int pos = n & ((1 << sl) - 1), seg = n >> sl;
    int rel = pos - grp;
    float v = 0.f;
    if (rel >= 0 && (rel & ((1 << grp) - 1)) == 0) {
      int tq = rel >> grp;
      int base = (grp == 2) ? 24 : (grp << 4);
      size_t inst = (size_t)(bb * 28 + base + hg * (4 >> grp) + seg);
      v = (float)og[inst * INST_STRIDE + (size_t)tq * 64 + lane];
    }
    vals[h] = v;
  }
  float sum = 0.f, sq = 0.f;
#pragma unroll
  for (int h = 0; h < 12; ++h) { sum += vals[h]; sq += vals[h] * vals[h]; }
#pragma unroll
  for (int mm = 32; mm; mm >>= 1) { sum += __shfl_xor(sum, mm); sq += __shfl_xor(sq, mm); }
  const float mu = sum * (1.f / 768.f);
  const float var = sq * (1.f / 768.f) - mu * mu;
  const float rstd = rsqrtf(var + 1e-5f);
  const int tok7 = tok & 7;
#pragma unroll
  for (int h = 0; h < 12; ++h) {
    int e = h * 64 + lane;
    float xn = (vals[h] - mu) * rstd * lnw[e] + lnb[e];
    int esw = h * 64 + ((((lane >> 3) ^ tok7) << 3) | (lane & 7));  // pre-swizzle for out_gemm
    xnorm[(size_t)tok * 768 + esw] = (bf16)xn;
  }
}

// ---------------- output projection GEMM (128x256 tile, 8 waves) ----------------
__launch_bounds__(512, 2)
__global__ void out_gemm(const bf16* __restrict__ xn, const bf16* __restrict__ wo,
                         const float* __restrict__ bo, float* __restrict__ out) {
  __shared__ __align__(16) bf16 lA[128 * 64];
  __shared__ __align__(16) bf16 lB[256 * 64];
  const int mt = blockIdx.x, nt = blockIdx.y;
  const int tid = threadIdx.x, lane = tid & 63, w = tid >> 6;
  const int wr = w >> 2, wc = w & 3;
  const int l15 = lane & 15, lg = lane >> 4;
  f32x4 acc[4][4];
#pragma unroll
  for (int i = 0; i < 4; ++i)
#pragma unroll
    for (int j = 0; j < 4; ++j) acc[i][j] = (f32x4){0.f, 0.f, 0.f, 0.f};

  for (int k0 = 0; k0 < 768; k0 += 64) {
#pragma unroll
    for (int j = 0; j < 2; ++j) {
      int region = w * 2 + j;
      int r = region * 8 + (lane >> 3);
      int cb = lane & 7;
      gload16(xn + (size_t)(mt * 128 + r) * 768 + k0 + cb * 8, (char*)lA + region * 1024);
    }
#pragma unroll
    for (int j = 0; j < 4; ++j) {
      int region = w * 4 + j;
      int r = region * 8 + (lane >> 3);
      int cb = lane & 7;
      gload16(wo + (size_t)(nt * 256 + r) * 768 + k0 + ((cb ^ (r & 7)) << 3), (char*)lB + region * 1024);
    }
    __syncthreads();
#pragma unroll
    for (int ks = 0; ks < 2; ++ks) {
      bf16x8 af[4], bfr[4];
#pragma unroll
      for (int i = 0; i < 4; ++i) {
        int row = wr * 64 + i * 16 + l15;
        af[i] = *(const bf16x8*)((const char*)lA + row * 128 + (((ks * 4 + lg) ^ (row & 7)) << 4));
        int col = wc * 64 + i * 16 + l15;
        bfr[i] = *(const bf16x8*)((const char*)lB + col * 128 + (((ks * 4 + lg) ^ (col & 7)) << 4));
      }
      __builtin_amdgcn_s_setprio(1);
#pragma unroll
      for (int i = 0; i < 4; ++i)
#pragma unroll
        for (int j = 0; j < 4; ++j) acc[i][j] = mfma16(af[i], bfr[j], acc[i][j]);
      __builtin_amdgcn_s_setprio(0);
    }
    __syncthreads();
  }
#pragma unroll
  for (int j = 0; j < 4; ++j) {
    int col = nt * 256 + wc * 64 + j * 16 + l15;
    float bias = bo[col];
#pragma unroll
    for (int i = 0; i < 4; ++i) {
      int row0 = mt * 128 + wr * 64 + i * 16 + (lg << 2);
#pragma unroll
      for (int reg = 0; reg < 4; ++reg)
        out[(size_t)(row0 + reg) * 768 + col] = acc[i][j][reg] + bias;
    }
  }
}

extern "C" void kernel_launch(void* const* d_in, const int* in_sizes, int n_in,
                              void* d_out, int out_size, void* d_ws, size_t ws_size,
                              hipStream_t stream) {
  (void)in_sizes; (void)n_in; (void)out_size; (void)ws_size;
  const float* query = (const float*)d_in[0];
  const float* key_  = (const float*)d_in[1];
  const float* value = (const float*)d_in[2];
  const float* Wqkv  = (const float*)d_in[3];
  const float* bqkv  = (const float*)d_in[4];
  const float* Wo    = (const float*)d_in[5];
  const float* bo    = (const float*)d_in[6];
  const float* lnw   = (const float*)d_in[7];
  const float* lnb   = (const float*)d_in[8];
  const int* flag    = (const int*)d_in[9];
  float* out = (float*)d_out;

  char* ws = (char*)d_ws;
  size_t off = 0;
  auto alloc = [&](size_t bytes) -> char* {
    char* p = ws + off;
    off += (bytes + 255) & ~(size_t)255;
    return p;
  };
  bf16* wq_bf  = (bf16*)alloc((size_t)3 * 768 * 768 * 2);
  bf16* wo_bf  = (bf16*)alloc((size_t)768 * 768 * 2);
  bf16* qg     = (bf16*)alloc((size_t)56 * INST_STRIDE * 2);
  bf16* kg     = (bf16*)alloc((size_t)56 * INST_STRIDE * 2);
  bf16* vtg    = (bf16*)alloc((size_t)56 * INST_STRIDE * 2);
  bf16* og     = (bf16*)alloc((size_t)56 * INST_STRIDE * 2);
  bf16* xnorm  = (bf16*)alloc((size_t)16384 * 768 * 2);

  convert_w<<<dim3(2304), dim3(256), 0, stream>>>(Wqkv, Wo, wq_bf, wo_bf);
  qkv_gemm<<<dim3(448, 1, 3), dim3(512), 0, stream>>>(query, key_, value, wq_bf, bqkv, qg, kg, vtg);
  attn<<<dim3(16, 56), dim3(256), 0, stream>>>(qg, kg, vtg, og, flag);
  ln_gather<<<dim3(4096), dim3(256), 0, stream>>>(og, lnw, lnb, xnorm);
  out_gemm<<<dim3(128, 3), dim3(512), 0, stream>>>(xnorm, wo_bf, bo, out);
}

// Round 21
// 204.559 us; speedup vs baseline: 1.0407x; 1.0407x over previous
//
#include <hip/hip_runtime.h>
#include <stdint.h>
#include <stddef.h>

typedef __bf16 bf16;
typedef __attribute__((ext_vector_type(4))) float f32x4;
typedef __attribute__((ext_vector_type(16))) float f32x16;
typedef __attribute__((ext_vector_type(8))) bf16 bf16x8;
typedef __attribute__((ext_vector_type(4))) bf16 bf16x4;

#define INST_STRIDE (2048 * 64)

static __device__ __forceinline__ f32x4 mfma16(bf16x8 a, bf16x8 b, f32x4 c) {
  return __builtin_amdgcn_mfma_f32_16x16x32_bf16(a, b, c, 0, 0, 0);
}
static __device__ __forceinline__ f32x16 mfma32(bf16x8 a, bf16x8 b, f32x16 c) {
  return __builtin_amdgcn_mfma_f32_32x32x16_bf16(a, b, c, 0, 0, 0);
}
static __device__ __forceinline__ void gload16(const void* g, void* l) {
  __builtin_amdgcn_global_load_lds(
      (const __attribute__((address_space(1))) void*)g,
      (__attribute__((address_space(3))) void*)l, 16, 0, 0);
}
static __device__ __forceinline__ float exp2_fast(float x) {
  float r;
  asm("v_exp_f32 %0, %1" : "=v"(r) : "v"(x));
  return r;
}

// ---------------- weight f32 -> bf16 convert ----------------
__global__ void convert_w(const float* __restrict__ Wqkv, const float* __restrict__ Wo,
                          bf16* __restrict__ wq, bf16* __restrict__ wo) {
  int idx = blockIdx.x * 256 + threadIdx.x;
  const int NQ = 3 * 768 * 768 / 4;
  const float4* src;
  bf16* dst;
  int i;
  if (idx < NQ) { src = (const float4*)Wqkv; dst = wq; i = idx; }
  else          { src = (const float4*)Wo;   dst = wo; i = idx - NQ; }
  float4 v = src[i];
  bf16x4 o = { (bf16)v.x, (bf16)v.y, (bf16)v.z, (bf16)v.w };
  *(bf16x4*)(dst + (size_t)i * 4) = o;
}

// ---------------- QKV GEMM over GATHERED rows (packed V AND Q stores) ----------------
// qg is d-major [d][tq] (like vtg, unswizzled) so Q stores pack to bf16x4.
__launch_bounds__(512, 2)
__global__ void qkv_gemm(const float* __restrict__ Xq, const float* __restrict__ Xk,
                         const float* __restrict__ Xv, const bf16* __restrict__ Wb,
                         const float* __restrict__ bqkv, bf16* __restrict__ qg,
                         bf16* __restrict__ kg, bf16* __restrict__ vtg) {
  __shared__ __align__(16) bf16 lA[128 * 64];   // 16 KB
  __shared__ __align__(16) bf16 lB[256 * 64];   // 32 KB
  const int z = blockIdx.z;
  const float* __restrict__ X = (z == 0) ? Xq : ((z == 1) ? Xk : Xv);
  const int bx = blockIdx.x;
  int g, mt;
  if (bx < 128)      { g = 0; mt = bx; }
  else if (bx < 192) { g = 1; mt = bx - 128; }
  else               { g = 2; mt = bx - 192; }
  const int gshift = 13 - g;
  const int gpbm = (8192 >> g) - 1;
  const int ibase = (g == 2) ? 24 : (g << 4);
  const int nseg = 4 >> g;

  const int tid = threadIdx.x;
  const int lane = tid & 63, w = tid >> 6;
  const int wr = w >> 2, wc = w & 3;
  const int l15 = lane & 15, lg = lane >> 4;

  auto maprow = [&](int G) -> size_t {
    int bb = G >> gshift;
    int loc = G & gpbm;
    int seg = loc >> 11, tq = loc & 2047;
    int token = (seg << (11 + g)) + g + (tq << g);
    return (size_t)(bb * 8192 + token);
  };

  const int c8 = tid & 7;
  size_t arow[2];
  int rr[2];
#pragma unroll
  for (int i = 0; i < 2; ++i) {
    rr[i] = i * 64 + (tid >> 3);
    arow[i] = maprow(mt * 128 + rr[i]);
  }

  f32x4 acc[4][4];
#pragma unroll
  for (int i = 0; i < 4; ++i)
#pragma unroll
    for (int j = 0; j < 4; ++j) acc[i][j] = (f32x4){0.f, 0.f, 0.f, 0.f};

  for (int t = 0; t < 12; ++t) {
    const int k0 = t * 64;
#pragma unroll
    for (int j = 0; j < 4; ++j) {
      int region = w * 4 + j;
      int row = region * 8 + (lane >> 3);
      int cb = lane & 7;
      const bf16* src = Wb + (size_t)(z * 768 + g * 256 + row) * 768 + k0 + ((cb ^ (row & 7)) << 3);
      gload16(src, (char*)lB + region * 1024);
    }
#pragma unroll
    for (int i = 0; i < 2; ++i) {
      const float* src = X + arow[i] * 768 + k0 + c8 * 8;
      float4 v0 = ((const float4*)src)[0];
      float4 v1 = ((const float4*)src)[1];
      bf16x8 o = { (bf16)v0.x, (bf16)v0.y, (bf16)v0.z, (bf16)v0.w,
                   (bf16)v1.x, (bf16)v1.y, (bf16)v1.z, (bf16)v1.w };
      *(bf16x8*)((char*)lA + rr[i] * 128 + ((c8 ^ (rr[i] & 7)) << 4)) = o;
    }
    __syncthreads();
#pragma unroll
    for (int ks = 0; ks < 2; ++ks) {
      bf16x8 af[4], bfr[4];
#pragma unroll
      for (int i = 0; i < 4; ++i) {
        int row = wr * 64 + i * 16 + l15;
        af[i] = *(const bf16x8*)((const char*)lA + row * 128 + (((ks * 4 + lg) ^ (row & 7)) << 4));
        int col = wc * 64 + i * 16 + l15;
        bfr[i] = *(const bf16x8*)((const char*)lB + col * 128 + (((ks * 4 + lg) ^ (col & 7)) << 4));
      }
      __builtin_amdgcn_s_setprio(1);
#pragma unroll
      for (int i = 0; i < 4; ++i)
#pragma unroll
        for (int j = 0; j < 4; ++j) acc[i][j] = mfma16(af[i], bfr[j], acc[i][j]);
      __builtin_amdgcn_s_setprio(0);
    }
    __syncthreads();
  }
  // epilogue: bias + direct store into gathered layouts (all rows valid).
#pragma unroll
  for (int j = 0; j < 4; ++j) {
    int col = wc * 64 + j * 16 + l15;
    float bias = bqkv[z * 768 + g * 256 + col];
    int hg = col >> 6, d = col & 63;
    int ho = ibase + hg * nseg;
#pragma unroll
    for (int i = 0; i < 4; ++i) {
      int G0 = mt * 128 + wr * 64 + i * 16 + (lg << 2);
      if (z == 2) {
        int bb = G0 >> gshift;
        int loc = G0 & gpbm;
        int seg = loc >> 11, tq = loc & 2047;
        size_t io = (size_t)(bb * 28 + ho + seg) * INST_STRIDE;
        int tsw = (tq & ~63) | ((((tq >> 3) & 7) ^ (d & 7)) << 3) | (tq & 7);
        bf16x4 pk = { (bf16)(acc[i][j][0] + bias), (bf16)(acc[i][j][1] + bias),
                      (bf16)(acc[i][j][2] + bias), (bf16)(acc[i][j][3] + bias) };
        *(bf16x4*)(vtg + io + (size_t)d * 2048 + tsw) = pk;
      } else if (z == 0) {
        // Q: d-major, packed, scaled into log2 domain (0.125 * log2(e))
        int bb = G0 >> gshift;
        int loc = G0 & gpbm;
        int seg = loc >> 11, tq = loc & 2047;
        size_t io = (size_t)(bb * 28 + ho + seg) * INST_STRIDE;
        const float s = 0.180336880f;
        bf16x4 pk = { (bf16)((acc[i][j][0] + bias) * s), (bf16)((acc[i][j][1] + bias) * s),
                      (bf16)((acc[i][j][2] + bias) * s), (bf16)((acc[i][j][3] + bias) * s) };
        *(bf16x4*)(qg + io + (size_t)d * 2048 + tq) = pk;
      } else {
#pragma unroll
        for (int reg = 0; reg < 4; ++reg) {
          int G = G0 + reg;
          int bb = G >> gshift;
          int loc = G & gpbm;
          int seg = loc >> 11, tq = loc & 2047;
          size_t io = (size_t)(bb * 28 + ho + seg) * INST_STRIDE;
          float v = acc[i][j][reg] + bias;
          int dsw = (d & 7) | (((d >> 3) ^ (tq & 7)) << 3);
          kg[io + tq * 64 + dsw] = (bf16)v;
        }
      }
    }
  }
}

// ---------------- flash attention: swapped-QK^T, no-max log2 softmax ----------------
#define CVTPK(lo_, hi_, out_) \
  asm("v_cvt_pk_bf16_f32 %0, %1, %2" : "=v"(out_) : "v"(lo_), "v"(hi_))

#define MAKE_PA(sv, kb2, dst)                                              \
  do {                                                                     \
    float p0 = exp2_fast(sv[kb2 * 8 + 0]);                                 \
    float p1 = exp2_fast(sv[kb2 * 8 + 1]);                                 \
    float p2 = exp2_fast(sv[kb2 * 8 + 2]);                                 \
    float p3 = exp2_fast(sv[kb2 * 8 + 3]);                                 \
    float p4 = exp2_fast(sv[kb2 * 8 + 4]);                                 \
    float p5 = exp2_fast(sv[kb2 * 8 + 5]);                                 \
    float p6 = exp2_fast(sv[kb2 * 8 + 6]);                                 \
    float p7 = exp2_fast(sv[kb2 * 8 + 7]);                                 \
    rs += (p0 + p1) + (p2 + p3) + ((p4 + p5) + (p6 + p7));                 \
    uint32_t a0, a1, a2, a3;                                               \
    CVTPK(p0, p1, a0); CVTPK(p2, p3, a1);                                  \
    CVTPK(p4, p5, a2); CVTPK(p6, p7, a3);                                  \
    asm("v_permlane32_swap_b32 %0, %1" : "+v"(a0), "+v"(a2));              \
    asm("v_permlane32_swap_b32 %0, %1" : "+v"(a1), "+v"(a3));              \
    union { uint32_t u[4]; bf16x8 v; } pk_;                                \
    pk_.u[0] = a0; pk_.u[1] = a1; pk_.u[2] = a2; pk_.u[3] = a3;            \
    dst = pk_.v;                                                           \
  } while (0)

__launch_bounds__(256, 2)
__global__ void attn(const bf16* __restrict__ qg, const bf16* __restrict__ kg,
                     const bf16* __restrict__ vtg, bf16* __restrict__ og,
                     const int* __restrict__ causal_p) {
  __shared__ __align__(16) bf16 lK[2][64 * 64];
  __shared__ __align__(16) bf16 lV[2][64 * 64];
  __shared__ float lSc[4][32];
  const int L = blockIdx.x + (blockIdx.y << 4);
  const int inst = (L & 7) * 7 + ((L >> 3) >> 4);
  const int qt = (L >> 3) & 15;
  const int tid = threadIdx.x, lane = tid & 63, w = tid >> 6;
  const int l31 = lane & 31, hi = lane >> 5;
  const int causal = causal_p[0];
  const size_t ib = (size_t)inst * INST_STRIDE;
  const int qbase = qt * 128 + w * 32;

  // Q fragments from d-major qg: lane owns q = qbase+l31; 8 d's per dt4.
  bf16x8 qf[4];
#pragma unroll
  for (int dt4 = 0; dt4 < 4; ++dt4) {
    bf16x8 v;
#pragma unroll
    for (int e = 0; e < 8; ++e)
      v[e] = qg[ib + (size_t)(dt4 * 16 + hi * 8 + e) * 2048 + qbase + l31];
    qf[dt4] = v;
  }

  int off0[4], off1[4];
#pragma unroll
  for (int c = 0; c < 4; ++c) {
    off0[c] = l31 * 128 + (((c * 2 + hi) ^ (l31 & 7)) << 4);
    off1[c] = (32 + l31) * 128 + (((c * 2 + hi) ^ (l31 & 7)) << 4);
  }

  f32x16 oacc0 = {0}, oacc1 = {0};
  float l = 0.f;

#define STAGE_AT(buf, kt_)                                                       \
  do {                                                                           \
    _Pragma("unroll") for (int j = 0; j < 2; ++j) {                              \
      int region = w * 2 + j;                                                    \
      int r = region * 8 + (lane >> 3);                                          \
      int cb = lane & 7;                                                         \
      gload16(kg + ib + (size_t)((kt_) + r) * 64 + cb * 8,                       \
              (char*)lK[buf] + region * 1024);                                   \
      gload16(vtg + ib + (size_t)r * 2048 + (kt_) + cb * 8,                      \
              (char*)lV[buf] + region * 1024);                                   \
    }                                                                            \
  } while (0)

  STAGE_AT(0, 0);
  __syncthreads();
  int cur = 0;
  for (int kt = 0; kt < 2048; kt += 64) {
    if (kt + 64 < 2048) STAGE_AT(cur ^ 1, kt + 64);
    const char* K = (const char*)lK[cur];
    const char* V = (const char*)lV[cur];
    f32x16 st0 = {0}, st1 = {0};
    __builtin_amdgcn_s_setprio(1);
#pragma unroll
    for (int dt4 = 0; dt4 < 4; ++dt4) {
      bf16x8 kf0 = *(const bf16x8*)(K + off0[dt4]);
      bf16x8 kf1 = *(const bf16x8*)(K + off1[dt4]);
      st0 = mfma32(kf0, qf[dt4], st0);
      st1 = mfma32(kf1, qf[dt4], st1);
    }
    __builtin_amdgcn_s_setprio(0);
    if (causal) {
      int q = qbase + l31;
#pragma unroll
      for (int r = 0; r < 16; ++r) {
        int kl = (r & 3) + 8 * (r >> 2) + 4 * hi;
        if (kt + kl > q) st0[r] = -1e30f;
        if (kt + 32 + kl > q) st1[r] = -1e30f;
      }
    }
    float rs = 0.f;
    bf16x8 pa0, pa1, pa2, pa3;
    MAKE_PA(st0, 0, pa0);
    MAKE_PA(st0, 1, pa1);
    MAKE_PA(st1, 0, pa2);
    MAKE_PA(st1, 1, pa3);
    rs += __shfl_xor(rs, 32);
    l += rs;
    __builtin_amdgcn_s_setprio(1);
#pragma unroll
    for (int kb = 0; kb < 4; ++kb) {
      bf16x8 pak = (kb == 0) ? pa0 : (kb == 1) ? pa1 : (kb == 2) ? pa2 : pa3;
      bf16x8 vf0 = *(const bf16x8*)(V + off0[kb]);
      bf16x8 vf1 = *(const bf16x8*)(V + off1[kb]);
      oacc0 = mfma32(pak, vf0, oacc0);
      oacc1 = mfma32(pak, vf1, oacc1);
    }
    __builtin_amdgcn_s_setprio(0);
    __syncthreads();
    cur ^= 1;
  }
  if (!hi) lSc[w][l31] = 1.f / l;
  asm volatile("s_waitcnt lgkmcnt(0)" ::: "memory");
  __builtin_amdgcn_sched_barrier(0);
#pragma unroll
  for (int r = 0; r < 16; ++r) {
    int ql = (r & 3) + 8 * (r >> 2) + 4 * hi;
    float linv = lSc[w][ql];
    int q = qbase + ql;
    og[ib + (size_t)q * 64 + l31] = (bf16)(oacc0[r] * linv);
    og[ib + (size_t)q * 64 + 32 + l31] = (bf16)(oacc1[r] * linv);
  }
}

// ---------------- gather + LayerNorm (one wave per token) ----------------
__global__ void ln_gather(const bf16* __restrict__ og, const float* __restrict__ lnw,
                          const float* __restrict__ lnb, bf16* __restrict__ xnorm) {
  const int tok = blockIdx.x * 4 + (threadIdx.x >> 6);
  const int lane = threadIdx.x & 63;
  const int bb = tok >> 13, n = tok & 8191;
  float vals[12];
#pragma unroll
  for (int h = 0; h < 12; ++h) {
    const int grp = h >> 2, hg = h & 3;
    const int sl = 11 + grp;
    int pos = n & ((1 << sl) - 1), seg = n >> sl;
    int rel = pos - grp;
    float v = 0.f;
    if (rel >= 0 && (rel & ((1 << grp) - 1)) == 0) {
      int tq = rel >> grp;
      int base = (grp == 2) ? 24 : (grp << 4);
      size_t inst = (size_t)(bb * 28 + base + hg * (4 >> grp) + seg);
      v = (float)og[inst * INST_STRIDE + (size_t)tq * 64 + lane];
    }
    vals[h] = v;
  }
  float sum = 0.f, sq = 0.f;
#pragma unroll
  for (int h = 0; h < 12; ++h) { sum += vals[h]; sq += vals[h] * vals[h]; }
#pragma unroll
  for (int mm = 32; mm; mm >>= 1) { sum += __shfl_xor(sum, mm); sq += __shfl_xor(sq, mm); }
  const float mu = sum * (1.f / 768.f);
  const float var = sq * (1.f / 768.f) - mu * mu;
  const float rstd = rsqrtf(var + 1e-5f);
  const int tok7 = tok & 7;
#pragma unroll
  for (int h = 0; h < 12; ++h) {
    int e = h * 64 + lane;
    float xn = (vals[h] - mu) * rstd * lnw[e] + lnb[e];
    int esw = h * 64 + ((((lane >> 3) ^ tok7) << 3) | (lane & 7));  // pre-swizzle for out_gemm
    xnorm[(size_t)tok * 768 + esw] = (bf16)xn;
  }
}

// ---------------- output projection GEMM (128x256 tile, 8 waves) ----------------
__launch_bounds__(512, 2)
__global__ void out_gemm(const bf16* __restrict__ xn, const bf16* __restrict__ wo,
                         const float* __restrict__ bo, float* __restrict__ out) {
  __shared__ __align__(16) bf16 lA[128 * 64];
  __shared__ __align__(16) bf16 lB[256 * 64];
  const int mt = blockIdx.x, nt = blockIdx.y;
  const int tid = threadIdx.x, lane = tid & 63, w = tid >> 6;
  const int wr = w >> 2, wc = w & 3;
  const int l15 = lane & 15, lg = lane >> 4;
  f32x4 acc[4][4];
#pragma unroll
  for (int i = 0; i < 4; ++i)
#pragma unroll
    for (int j = 0; j < 4; ++j) acc[i][j] = (f32x4){0.f, 0.f, 0.f, 0.f};

  for (int k0 = 0; k0 < 768; k0 += 64) {
#pragma unroll
    for (int j = 0; j < 2; ++j) {
      int region = w * 2 + j;
      int r = region * 8 + (lane >> 3);
      int cb = lane & 7;
      gload16(xn + (size_t)(mt * 128 + r) * 768 + k0 + cb * 8, (char*)lA + region * 1024);
    }
#pragma unroll
    for (int j = 0; j < 4; ++j) {
      int region = w * 4 + j;
      int r = region * 8 + (lane >> 3);
      int cb = lane & 7;
      gload16(wo + (size_t)(nt * 256 + r) * 768 + k0 + ((cb ^ (r & 7)) << 3), (char*)lB + region * 1024);
    }
    __syncthreads();
#pragma unroll
    for (int ks = 0; ks < 2; ++ks) {
      bf16x8 af[4], bfr[4];
#pragma unroll
      for (int i = 0; i < 4; ++i) {
        int row = wr * 64 + i * 16 + l15;
        af[i] = *(const bf16x8*)((const char*)lA + row * 128 + (((ks * 4 + lg) ^ (row & 7)) << 4));
        int col = wc * 64 + i * 16 + l15;
        bfr[i] = *(const bf16x8*)((const char*)lB + col * 128 + (((ks * 4 + lg) ^ (col & 7)) << 4));
      }
      __builtin_amdgcn_s_setprio(1);
#pragma unroll
      for (int i = 0; i < 4; ++i)
#pragma unroll
        for (int j = 0; j < 4; ++j) acc[i][j] = mfma16(af[i], bfr[j], acc[i][j]);
      __builtin_amdgcn_s_setprio(0);
    }
    __syncthreads();
  }
#pragma unroll
  for (int j = 0; j < 4; ++j) {
    int col = nt * 256 + wc * 64 + j * 16 + l15;
    float bias = bo[col];
#pragma unroll
    for (int i = 0; i < 4; ++i) {
      int row0 = mt * 128 + wr * 64 + i * 16 + (lg << 2);
#pragma unroll
      for (int reg = 0; reg < 4; ++reg)
        out[(size_t)(row0 + reg) * 768 + col] = acc[i][j][reg] + bias;
    }
  }
}

extern "C" void kernel_launch(void* const* d_in, const int* in_sizes, int n_in,
                              void* d_out, int out_size, void* d_ws, size_t ws_size,
                              hipStream_t stream) {
  (void)in_sizes; (void)n_in; (void)out_size; (void)ws_size;
  const float* query = (const float*)d_in[0];
  const float* key_  = (const float*)d_in[1];
  const float* value = (const float*)d_in[2];
  const float* Wqkv  = (const float*)d_in[3];
  const float* bqkv  = (const float*)d_in[4];
  const float* Wo    = (const float*)d_in[5];
  const float* bo    = (const float*)d_in[6];
  const float* lnw   = (const float*)d_in[7];
  const float* lnb   = (const float*)d_in[8];
  const int* flag    = (const int*)d_in[9];
  float* out = (float*)d_out;

  char* ws = (char*)d_ws;
  size_t off = 0;
  auto alloc = [&](size_t bytes) -> char* {
    char* p = ws + off;
    off += (bytes + 255) & ~(size_t)255;
    return p;
  };
  bf16* wq_bf  = (bf16*)alloc((size_t)3 * 768 * 768 * 2);
  bf16* wo_bf  = (bf16*)alloc((size_t)768 * 768 * 2);
  bf16* qg     = (bf16*)alloc((size_t)56 * INST_STRIDE * 2);
  bf16* kg     = (bf16*)alloc((size_t)56 * INST_STRIDE * 2);
  bf16* vtg    = (bf16*)alloc((size_t)56 * INST_STRIDE * 2);
  bf16* og     = (bf16*)alloc((size_t)56 * INST_STRIDE * 2);
  bf16* xnorm  = (bf16*)alloc((size_t)16384 * 768 * 2);

  convert_w<<<dim3(2304), dim3(256), 0, stream>>>(Wqkv, Wo, wq_bf, wo_bf);
  qkv_gemm<<<dim3(224, 1, 3), dim3(512), 0, stream>>>(query, key_, value, wq_bf, bqkv, qg, kg, vtg);
  attn<<<dim3(16, 56), dim3(256), 0, stream>>>(qg, kg, vtg, og, flag);
  ln_gather<<<dim3(4096), dim3(256), 0, stream>>>(og, lnw, lnb, xnorm);
  out_gemm<<<dim3(128, 3), dim3(512), 0, stream>>>(xnorm, wo_bf, bo, out);
}